// Round 13
// baseline (543.996 us; speedup 1.0000x reference)
//
#include <hip/hip_runtime.h>
#include <cmath>

namespace {

constexpr int L = 8, H = 1536, W = 1536, HW = H * W, C = 12;
constexpr int TWB = 128, TH = 16;          // block output tile 128x16
constexpr int LH = TH + 10;                // 26 tile rows
constexpr int LPAD = 8;                    // left halo padded to 8 for 16B alignment
constexpr int LCOLS = 148;                 // 36 float4 data slots (144) + 4 pad

// nonzero-tap extents of the 11x11 disc (dist<=5)
__device__ __host__ constexpr int XLO[11]  = {5, 2, 1, 1, 1, 0, 1, 1, 1, 2, 5};
__device__ __host__ constexpr int XHI[11]  = {5, 8, 9, 9, 9,10, 9, 9, 9, 8, 5};
__device__ __host__ constexpr int WOFF[11] = {0, 1, 8,17,26,35,46,55,64,73,80}; // 81 total

// fixed topology from the reference (_PAIRS)
__device__ constexpr int CSRC[C] = {0,1,2,3,4,5,6,0,2,4,7,3};
__device__ constexpr int CDST[C] = {1,2,3,4,5,6,7,2,4,6,0,5};

struct Weights { float w[81]; };

// ---------------- fast kernel: <=64-VGPR structural target ----------------
__global__ __launch_bounds__(256)   // NO min-waves pin (rounds 2/6/9 lesson)
void snn_fast(const float* __restrict__ ext,
              const float* __restrict__ spk,
              const float* __restrict__ mem,
              const float* __restrict__ iw,
              const int*   __restrict__ refr,
              float* __restrict__ out,
              unsigned*    wslist,          // [0]=count, [1..cap]=gidx list
              unsigned     cap,
              const Weights wt)
{
    __shared__ float tile[LH][LCOLS];

    const int tx = threadIdx.x;          // 0..31
    const int ty = threadIdx.y;          // 0..7
    const int tid = ty * 32 + tx;
    const int bx = blockIdx.x, by = blockIdx.y, l = blockIdx.z;

    // ---- stage spike tile: aligned float4 path, edge fallback ----
    const int gx0 = bx * TWB - LPAD;     // global x of tile col 0 (16B aligned)
    const int gy0 = by * TH - 5;
    const float* sp_l = spk + l * HW;
    for (int idx = tid; idx < LH * 36; idx += 256) {
        const int r    = idx / 36;
        const int slot = idx - r * 36;
        const int gy = gy0 + r;
        const int gx = gx0 + 4 * slot;
        float4 v = make_float4(0.f, 0.f, 0.f, 0.f);
        if ((unsigned)gy < (unsigned)H) {
            const float* src = sp_l + gy * W;
            if (gx >= 0 && gx + 3 < W) {
                v = *(const float4*)(src + gx);       // 16B aligned
            } else {
                float t0 = 0.f, t1 = 0.f, t2 = 0.f, t3 = 0.f;
                if ((unsigned)(gx + 0) < (unsigned)W) t0 = src[gx + 0];
                if ((unsigned)(gx + 1) < (unsigned)W) t1 = src[gx + 1];
                if ((unsigned)(gx + 2) < (unsigned)W) t2 = src[gx + 2];
                if ((unsigned)(gx + 3) < (unsigned)W) t3 = src[gx + 3];
                v = make_float4(t0, t1, t2, t3);
            }
        }
        *(float4*)&tile[r][4 * slot] = v;             // 16B aligned
    }

    const int ox    = bx * TWB + 4 * tx;
    const int oy0   = by * TH + ty * 2;
    const int pidx0 = oy0 * W + ox;
    const int gidx0 = l * HW + pidx0;

    // ---- seed phase BEFORE barrier (independent of LDS):
    //      acc = 0.9*m + e + axonal ; refr -> 1-reg mask ----
    float acc[2][4];
    unsigned mask = 0;
    #pragma unroll
    for (int k = 0; k < 2; ++k) {
        const int gidx = gidx0 + k * W;
        const int pidx = pidx0 + k * W;
        const int4   rf4 = *(const int4*)  (refr + gidx);
        const float4 e4  = *(const float4*)(ext  + gidx);
        const float4 m4  = *(const float4*)(mem  + gidx);
        acc[k][0] = fmaf(0.9f, m4.x, e4.x);
        acc[k][1] = fmaf(0.9f, m4.y, e4.y);
        acc[k][2] = fmaf(0.9f, m4.z, e4.z);
        acc[k][3] = fmaf(0.9f, m4.w, e4.w);
        mask |= (rf4.x == 0 ? 1u : 0u) << (k * 4 + 0);
        mask |= (rf4.y == 0 ? 1u : 0u) << (k * 4 + 1);
        mask |= (rf4.z == 0 ? 1u : 0u) << (k * 4 + 2);
        mask |= (rf4.w == 0 ? 1u : 0u) << (k * 4 + 3);
        #pragma unroll
        for (int c = 0; c < C; ++c) {
            if (CDST[c] != l) continue;               // block-uniform
            const float4 s4 = *(const float4*)(spk + CSRC[c] * HW + pidx);
            const float4 w4 = *(const float4*)(iw  + c       * HW + pidx);
            acc[k][0] += s4.x * w4.x; acc[k][1] += s4.y * w4.y;
            acc[k][2] += s4.z * w4.z; acc[k][3] += s4.w * w4.w;
        }
    }
    __syncthreads();

    // ---- conv: split-window passes keep only 12 floats live ----
    #pragma unroll
    for (int j = 0; j < 12; ++j) {                    // tile row = ty*2 + j
        const float* row = &tile[ty * 2 + j][4 * tx];
        // pass A: dx in [XLO..4] -> cols 3..11 (quads 0..2)
        {
            alignas(16) float wa[12];
            *(float4*)&wa[0] = *(const float4*)(row + 0);
            *(float4*)&wa[4] = *(const float4*)(row + 4);
            *(float4*)&wa[8] = *(const float4*)(row + 8);
            #pragma unroll
            for (int k = 0; k < 2; ++k) {
                const int dy = j - k;
                if (dy < 0 || dy > 10) continue;      // compile-time pruned
                #pragma unroll
                for (int dx = XLO[dy]; dx <= 4; ++dx) {
                    const float wv = wt.w[WOFF[dy] + dx - XLO[dy]];  // SGPR
                    #pragma unroll
                    for (int c = 0; c < 4; ++c)
                        acc[k][c] += wv * wa[3 + c + dx];
                }
            }
        }
        // pass B: dx in [5..XHI] -> cols 8..17 (quads 2,3 + col 16)
        {
            alignas(16) float wb[12];                 // wb[i] = col 8+i
            *(float4*)&wb[0] = *(const float4*)(row + 8);
            *(float4*)&wb[4] = *(const float4*)(row + 12);
            wb[8] = row[16];
            #pragma unroll
            for (int k = 0; k < 2; ++k) {
                const int dy = j - k;
                if (dy < 0 || dy > 10) continue;      // compile-time pruned
                #pragma unroll
                for (int dx = 5; dx <= XHI[dy]; ++dx) {
                    const float wv = wt.w[WOFF[dy] + dx - XLO[dy]];  // SGPR
                    #pragma unroll
                    for (int c = 0; c < 4; ++c)
                        acc[k][c] += wv * wb[c + dx - 5];  // col 3+c+dx = 8 + (c+dx-5)
                }
            }
        }
    }

    // ---- tail: pure arithmetic, no global loads ----
    #pragma unroll
    for (int k = 0; k < 2; ++k) {
        const int gidx = gidx0 + k * W;
        float res[4];
        #pragma unroll
        for (int c = 0; c < 4; ++c) {
            const bool act = (mask >> (k * 4 + c)) & 1u;
            const float v = acc[k][c];
            res[c] = (act && v > 0.f) ? 1.f : 0.f;
            if (act && __builtin_expect(fabsf(v) < 1e-3f, 0)) {
                const unsigned idx = atomicAdd(wslist, 1u);
                if (idx < cap) wslist[1 + idx] = (unsigned)(gidx + c);
            }
        }
        *(float4*)(out + gidx) = make_float4(res[0], res[1], res[2], res[3]);
    }
}

// ---------------- fixup kernel: exact f64 recompute of flagged pixels ----------------
__global__ __launch_bounds__(256)
void snn_fixup(const float* __restrict__ ext,
               const float* __restrict__ spk,
               const float* __restrict__ mem,
               const float* __restrict__ iw,
               const float* __restrict__ lk,
               float* __restrict__ out,
               const unsigned* __restrict__ wslist,
               unsigned cap)
{
    const unsigned n = min(wslist[0], cap);
    for (unsigned i = blockIdx.x * blockDim.x + threadIdx.x; i < n;
         i += gridDim.x * blockDim.x) {
        const unsigned gidx = wslist[1 + i];
        const int l    = gidx / HW;
        const int pidx = gidx - l * HW;
        const int oy   = pidx / W;
        const int ox   = pidx - oy * W;

        const float* sp = spk + l * HW;
        double conv = 0.0;
        for (int dy = 0; dy < 11; ++dy) {
            const int yy = oy + dy - 5;
            if ((unsigned)yy >= (unsigned)H) continue;
            for (int dx = 0; dx < 11; ++dx) {
                const int xx = ox + dx - 5;
                if ((unsigned)xx >= (unsigned)W) continue;
                conv += (double)lk[dy * 11 + dx] * (double)sp[yy * W + xx];
            }
        }
        double ax = 0.0;
        #pragma unroll
        for (int c = 0; c < C; ++c)
            if (CDST[c] == l)
                ax += (double)spk[CSRC[c] * HW + pidx] * (double)iw[c * HW + pidx];
        const double tot = ((double)ext[gidx] + conv) + ax;
        const double vd  = 0.9 * (double)mem[gidx] + tot;
        out[gidx] = (vd > 0.0) ? 1.f : 0.f;
    }
}

} // namespace

extern "C" void kernel_launch(void* const* d_in, const int* in_sizes, int n_in,
                              void* d_out, int out_size, void* d_ws, size_t ws_size,
                              hipStream_t stream) {
    const float* ext  = (const float*)d_in[0];
    const float* spk  = (const float*)d_in[1];
    const float* mem  = (const float*)d_in[2];
    const float* iw   = (const float*)d_in[3];
    const float* lk   = (const float*)d_in[4];
    const int*   refr = (const int*)  d_in[5];
    float* o = (float*)d_out;

    // host-side f64 weight computation, mirroring numpy
    Weights wt;
    for (int dy = 0; dy < 11; ++dy) {
        for (int dx = XLO[dy]; dx <= XHI[dy]; ++dx) {
            const double ddy = dy - 5, ddx = dx - 5;
            const double dist = std::sqrt(ddy * ddy + ddx * ddx);
            double w = std::exp(-dist / 2.0);
            if (dist > 5.0) w = 0.0;
            if (dy == 5 && dx == 5) w = 0.0;
            wt.w[WOFF[dy] + dx - XLO[dy]] = (float)w;
        }
    }

    dim3 grid(W / TWB, H / TH, L);   // (12, 96, 8)
    dim3 block(32, 8, 1);

    unsigned* wsl = (unsigned*)d_ws;
    size_t cap64 = ws_size / 4 - 1;
    const unsigned cap = (unsigned)(cap64 > 0x7FFFFFFFu ? 0x7FFFFFFFu : cap64);
    hipMemsetAsync(d_ws, 0, 4, stream);   // zero the counter (graph-safe)
    hipLaunchKernelGGL(snn_fast, grid, block, 0, stream,
                       ext, spk, mem, iw, refr, o, wsl, cap, wt);
    hipLaunchKernelGGL(snn_fixup, dim3(64), dim3(256), 0, stream,
                       ext, spk, mem, iw, lk, o, wsl, cap);
}

// Round 14
// 270.879 us; speedup vs baseline: 2.0083x; 2.0083x over previous
//
#include <hip/hip_runtime.h>
#include <cmath>

namespace {

constexpr int L = 8, H = 1536, W = 1536, HW = H * W, C = 12;
constexpr int TWB = 128, TH = 16;          // block output tile 128x16
constexpr int LH = TH + 10;                // 26 tile rows
constexpr int LPAD = 8;                    // left halo padded to 8 for 16B alignment
constexpr int LSTR = 144;                  // LINEAR row stride (floats); 2-way alias free
constexpr int NSLOT = 36;                  // float4 slots per row
constexpr int NSTG  = LH * NSLOT;          // 936 float4 slots = 15 x 1KB chunks (last partial)
constexpr int LDSF  = 27 * 144;            // 3888 floats: chunk-14 tail lands in row 26 (unread)

// nonzero-tap extents of the 11x11 disc (dist<=5)
__device__ __host__ constexpr int XLO[11]  = {5, 2, 1, 1, 1, 0, 1, 1, 1, 2, 5};
__device__ __host__ constexpr int XHI[11]  = {5, 8, 9, 9, 9,10, 9, 9, 9, 8, 5};
__device__ __host__ constexpr int WOFF[11] = {0, 1, 8,17,26,35,46,55,64,73,80}; // 81 total

// fixed topology from the reference (_PAIRS)
__device__ constexpr int CSRC[C] = {0,1,2,3,4,5,6,0,2,4,7,3};
__device__ constexpr int CDST[C] = {1,2,3,4,5,6,7,2,4,6,0,5};

struct Weights { float w[81]; };

// ---- shared body: seed (after barrier) + win-20 conv + mask tail (round-12) ----
__device__ __forceinline__ void snn_body(const float* __restrict__ tile,
    int tx, int ty, int bx, int by, int l,
    const float* __restrict__ ext, const float* __restrict__ spk,
    const float* __restrict__ mem, const float* __restrict__ iw,
    const int*   __restrict__ refr, float* __restrict__ out,
    unsigned* wslist, unsigned cap, const Weights& wt)
{
    const int ox    = bx * TWB + 4 * tx;
    const int oy0   = by * TH + ty * 2;
    const int pidx0 = oy0 * W + ox;
    const int gidx0 = l * HW + pidx0;

    // seed: acc = 0.9*m + e + axonal ; refr -> 1-reg mask
    float acc[2][4];
    unsigned mask = 0;
    #pragma unroll
    for (int k = 0; k < 2; ++k) {
        const int gidx = gidx0 + k * W;
        const int pidx = pidx0 + k * W;
        const int4   rf4 = *(const int4*)  (refr + gidx);
        const float4 e4  = *(const float4*)(ext  + gidx);
        const float4 m4  = *(const float4*)(mem  + gidx);
        acc[k][0] = fmaf(0.9f, m4.x, e4.x);
        acc[k][1] = fmaf(0.9f, m4.y, e4.y);
        acc[k][2] = fmaf(0.9f, m4.z, e4.z);
        acc[k][3] = fmaf(0.9f, m4.w, e4.w);
        mask |= (rf4.x == 0 ? 1u : 0u) << (k * 4 + 0);
        mask |= (rf4.y == 0 ? 1u : 0u) << (k * 4 + 1);
        mask |= (rf4.z == 0 ? 1u : 0u) << (k * 4 + 2);
        mask |= (rf4.w == 0 ? 1u : 0u) << (k * 4 + 3);
        #pragma unroll
        for (int c = 0; c < C; ++c) {
            if (CDST[c] != l) continue;               // block-uniform
            const float4 s4 = *(const float4*)(spk + CSRC[c] * HW + pidx);
            const float4 w4 = *(const float4*)(iw  + c       * HW + pidx);
            acc[k][0] += s4.x * w4.x; acc[k][1] += s4.y * w4.y;
            acc[k][2] += s4.z * w4.z; acc[k][3] += s4.w * w4.w;
        }
    }

    // conv: 4 cols x 2 rows per thread, b128 window loads
    #pragma unroll
    for (int j = 0; j < 12; ++j) {                    // tile row = ty*2 + j
        const float* row = tile + (ty * 2 + j) * LSTR + 4 * tx;
        alignas(16) float win[20];
        *(float4*)&win[0]  = *(const float4*)(row + 0);
        *(float4*)&win[4]  = *(const float4*)(row + 4);
        *(float4*)&win[8]  = *(const float4*)(row + 8);
        *(float4*)&win[12] = *(const float4*)(row + 12);
        win[16] = row[16];
        #pragma unroll
        for (int k = 0; k < 2; ++k) {
            const int dy = j - k;
            if (dy < 0 || dy > 10) continue;          // compile-time pruned
            #pragma unroll
            for (int dx = XLO[dy]; dx <= XHI[dy]; ++dx) {
                const float wv = wt.w[WOFF[dy] + dx - XLO[dy]];  // SGPR
                #pragma unroll
                for (int c = 0; c < 4; ++c)
                    acc[k][c] += wv * win[3 + c + dx];  // window base offset 3
            }
        }
    }

    // tail: pure arithmetic, no global loads
    #pragma unroll
    for (int k = 0; k < 2; ++k) {
        const int gidx = gidx0 + k * W;
        float res[4];
        #pragma unroll
        for (int c = 0; c < 4; ++c) {
            const bool act = (mask >> (k * 4 + c)) & 1u;
            const float v = acc[k][c];
            res[c] = (act && v > 0.f) ? 1.f : 0.f;
            if (act && __builtin_expect(fabsf(v) < 1e-3f, 0)) {
                const unsigned idx = atomicAdd(wslist, 1u);
                if (idx < cap) wslist[1 + idx] = (unsigned)(gidx + c);
            }
        }
        *(float4*)(out + gidx) = make_float4(res[0], res[1], res[2], res[3]);
    }
}

typedef const __attribute__((address_space(1))) void* gvp;
typedef __attribute__((address_space(3)))       void* lvp;

// ---------------- interior kernel: global_load_lds staging, zero guards ----------------
__global__ __launch_bounds__(256)
void snn_fast_int(const float* __restrict__ ext,
                  const float* __restrict__ spk,
                  const float* __restrict__ mem,
                  const float* __restrict__ iw,
                  const int*   __restrict__ refr,
                  float* __restrict__ out,
                  unsigned* wslist, unsigned cap,
                  const Weights wt)
{
    __shared__ float tile[LDSF];

    const int tx = threadIdx.x;          // 0..31
    const int ty = threadIdx.y;          // 0..7
    const int tid = ty * 32 + tx;
    const int bx = blockIdx.x + 1;       // 1..10
    const int by = blockIdx.y + 1;       // 1..94
    const int l  = blockIdx.z;

    const int gx0 = bx * TWB - LPAD;
    const int gy0 = by * TH - 5;
    const float* sp_l = spk + l * HW;

    const int wv   = tid >> 6;           // wave id 0..3 (wave-uniform)
    const int lane = tid & 63;
    #pragma unroll
    for (int i = 0; i < 4; ++i) {
        const int ch = wv + 4 * i;       // 1KB chunk index, wave-uniform
        if (ch < 15) {                   // uniform branch; chunk 15 unused
            const int idx = ch * 64 + lane;
            const int r = idx / NSLOT;
            const int s = idx - r * NSLOT;
            const float* src = sp_l + (gy0 + r) * W + (gx0 + 4 * s);
            __builtin_amdgcn_global_load_lds((gvp)src, (lvp)(tile + ch * 256),
                                             16, 0, 0);
        }
    }
    __syncthreads();

    snn_body(tile, tx, ty, bx, by, l, ext, spk, mem, iw, refr, out,
             wslist, cap, wt);
}

// ---------------- edge kernel: guarded register staging (same linear layout) ----------------
__global__ __launch_bounds__(256)
void snn_fast_edge(const float* __restrict__ ext,
                   const float* __restrict__ spk,
                   const float* __restrict__ mem,
                   const float* __restrict__ iw,
                   const int*   __restrict__ refr,
                   float* __restrict__ out,
                   unsigned* wslist, unsigned cap,
                   const Weights wt)
{
    __shared__ float tile[LDSF];

    const int bx = blockIdx.x, by = blockIdx.y, l = blockIdx.z;
    if (bx >= 1 && bx <= 10 && by >= 1 && by <= 94) return;  // interior elsewhere

    const int tx = threadIdx.x;
    const int ty = threadIdx.y;
    const int tid = ty * 32 + tx;
    const int gx0 = bx * TWB - LPAD;
    const int gy0 = by * TH - 5;
    const float* sp_l = spk + l * HW;

    for (int idx = tid; idx < NSTG; idx += 256) {
        const int r = idx / NSLOT;
        const int s = idx - r * NSLOT;
        const int gy = gy0 + r;
        const int gx = gx0 + 4 * s;
        float4 v = make_float4(0.f, 0.f, 0.f, 0.f);
        if ((unsigned)gy < (unsigned)H) {
            const float* src = sp_l + gy * W;
            if (gx >= 0 && gx + 3 < W) {
                v = *(const float4*)(src + gx);
            } else {
                if ((unsigned)(gx + 0) < (unsigned)W) v.x = src[gx + 0];
                if ((unsigned)(gx + 1) < (unsigned)W) v.y = src[gx + 1];
                if ((unsigned)(gx + 2) < (unsigned)W) v.z = src[gx + 2];
                if ((unsigned)(gx + 3) < (unsigned)W) v.w = src[gx + 3];
            }
        }
        *(float4*)&tile[r * LSTR + 4 * s] = v;
    }
    __syncthreads();

    snn_body(tile, tx, ty, bx, by, l, ext, spk, mem, iw, refr, out,
             wslist, cap, wt);
}

// ---------------- fixup kernel: exact f64 recompute of flagged pixels ----------------
__global__ __launch_bounds__(256)
void snn_fixup(const float* __restrict__ ext,
               const float* __restrict__ spk,
               const float* __restrict__ mem,
               const float* __restrict__ iw,
               const float* __restrict__ lk,
               float* __restrict__ out,
               const unsigned* __restrict__ wslist,
               unsigned cap)
{
    const unsigned n = min(wslist[0], cap);
    for (unsigned i = blockIdx.x * blockDim.x + threadIdx.x; i < n;
         i += gridDim.x * blockDim.x) {
        const unsigned gidx = wslist[1 + i];
        const int l    = gidx / HW;
        const int pidx = gidx - l * HW;
        const int oy   = pidx / W;
        const int ox   = pidx - oy * W;

        const float* sp = spk + l * HW;
        double conv = 0.0;
        for (int dy = 0; dy < 11; ++dy) {
            const int yy = oy + dy - 5;
            if ((unsigned)yy >= (unsigned)H) continue;
            for (int dx = 0; dx < 11; ++dx) {
                const int xx = ox + dx - 5;
                if ((unsigned)xx >= (unsigned)W) continue;
                conv += (double)lk[dy * 11 + dx] * (double)sp[yy * W + xx];
            }
        }
        double ax = 0.0;
        #pragma unroll
        for (int c = 0; c < C; ++c)
            if (CDST[c] == l)
                ax += (double)spk[CSRC[c] * HW + pidx] * (double)iw[c * HW + pidx];
        const double tot = ((double)ext[gidx] + conv) + ax;
        const double vd  = 0.9 * (double)mem[gidx] + tot;
        out[gidx] = (vd > 0.0) ? 1.f : 0.f;
    }
}

} // namespace

extern "C" void kernel_launch(void* const* d_in, const int* in_sizes, int n_in,
                              void* d_out, int out_size, void* d_ws, size_t ws_size,
                              hipStream_t stream) {
    const float* ext  = (const float*)d_in[0];
    const float* spk  = (const float*)d_in[1];
    const float* mem  = (const float*)d_in[2];
    const float* iw   = (const float*)d_in[3];
    const float* lk   = (const float*)d_in[4];
    const int*   refr = (const int*)  d_in[5];
    float* o = (float*)d_out;

    // host-side f64 weight computation, mirroring numpy
    Weights wt;
    for (int dy = 0; dy < 11; ++dy) {
        for (int dx = XLO[dy]; dx <= XHI[dy]; ++dx) {
            const double ddy = dy - 5, ddx = dx - 5;
            const double dist = std::sqrt(ddy * ddy + ddx * ddx);
            double w = std::exp(-dist / 2.0);
            if (dist > 5.0) w = 0.0;
            if (dy == 5 && dx == 5) w = 0.0;
            wt.w[WOFF[dy] + dx - XLO[dy]] = (float)w;
        }
    }

    dim3 blk(32, 8, 1);
    dim3 gi(10, 94, 8);              // interior blocks (bx 1..10, by 1..94)
    dim3 ge(W / TWB, H / TH, 8);     // full grid; interior early-exits

    unsigned* wsl = (unsigned*)d_ws;
    size_t cap64 = ws_size / 4 - 1;
    const unsigned cap = (unsigned)(cap64 > 0x7FFFFFFFu ? 0x7FFFFFFFu : cap64);
    hipMemsetAsync(d_ws, 0, 4, stream);   // zero the counter (graph-safe)
    hipLaunchKernelGGL(snn_fast_int,  gi, blk, 0, stream,
                       ext, spk, mem, iw, refr, o, wsl, cap, wt);
    hipLaunchKernelGGL(snn_fast_edge, ge, blk, 0, stream,
                       ext, spk, mem, iw, refr, o, wsl, cap, wt);
    hipLaunchKernelGGL(snn_fixup, dim3(64), dim3(256), 0, stream,
                       ext, spk, mem, iw, lk, o, wsl, cap);
}